// Round 7
// baseline (447.861 us; speedup 1.0000x reference)
//
#include <hip/hip_runtime.h>
#include <hip/hip_bf16.h>

typedef __bf16 bf16_t;
typedef __bf16 bf16x8 __attribute__((ext_vector_type(8)));
typedef __bf16 bf16x4 __attribute__((ext_vector_type(4)));
typedef float f32x16 __attribute__((ext_vector_type(16)));

#define QS   256.0f
#define QINV 0.00390625f

__device__ __forceinline__ void async_copy16(const bf16_t* g, bf16_t* l) {
  __builtin_amdgcn_global_load_lds(
      (__attribute__((address_space(1))) void*)g,
      (__attribute__((address_space(3))) void*)l,
      16, 0, 0);
}

// C = quantize-epilogue(A @ Bt^T + bias)
// A:  [M][K] bf16 row-major; Bt: [N][K] bf16 row-major (B transposed)
// 32x32x16 MFMA (2x FLOP/inst vs 16x16x32; 2495 vs 2176 TF ubench ceiling);
// wave computes 64x64 as 2x2 tiles of 32x32.
// LDS XOR swizzle: 16B chunk c of row r stored at phys chunk c ^ (r & 7)
// (staged by permuting which GLOBAL chunk each lane fetches; read side
// xors back). 64 lanes hit 64 distinct 16B slots per frag read ->
// bank-conflict-free (same distribution as verified 16x16 version).
// A-frag (lane l): row = l&31, k-chunk = (l>>5); B symmetric.
// C/D [m74/m101 verified]: col=lane&31, row=(reg&3)+8*(reg>>2)+4*(lane>>5).
// GELU PWL table lives in REGISTERS (lane l holds Yt[l] / slope[l]).
template <bool GELU, typename OutT, bool XSWZ>
__global__ __launch_bounds__(256, 3)
void gemm_tile(const bf16_t* __restrict__ A, const bf16_t* __restrict__ Bt,
               const float* __restrict__ bias, OutT* __restrict__ C,
               int M, int N, int K) {
  __shared__ __attribute__((aligned(16))) bf16_t As[128 * 64];
  __shared__ __attribute__((aligned(16))) bf16_t Bs[128 * 64];

  const int tid = threadIdx.x;
  const int lane = tid & 63;
  const int wv = tid >> 6;
  const int wy = wv >> 1;   // wave row (0/1) -> 64 rows
  const int wx = wv & 1;    // wave col (0/1) -> 64 cols
  const int l31 = lane & 31;
  const int lh = lane >> 5; // k-chunk half (0/1)

  // register-resident PWL table: lane l holds y(x_l) and slope to x_{l+1}
  float ytA = 0.f, ytS = 0.f;
  if (GELU) {
    float xv = -4.0f + 0.25f * (float)lane;
    float y0 = 0.5f * xv * (1.0f + erff(xv * 0.70710678f));
    float xv1 = xv + 0.25f;
    float y1 = 0.5f * xv1 * (1.0f + erff(xv1 * 0.70710678f));
    ytA = y0;
    ytS = y1 - y0;
  }

  int bx = blockIdx.x, by = blockIdx.y;
  if (XSWZ) {
    // bijective XCD-chunked remap. NOTE (r6 post-mortem): helps only when
    // the per-XCD reuse panel fits 4MB L2 (GEMM2: D=1024 -> B-panel 1MB).
    // HURTS GEMM1 (w1t 8.4MB/XCD streams) -> GEMM1 uses XSWZ=false.
    const int gx = gridDim.x;
    const int nwg = gx * gridDim.y;       // divisible by 8 here
    const int f = by * gx + bx;
    const int chunk = nwg >> 3;
    const int f2 = (f & 7) * chunk + (f >> 3);
    bx = f2 % gx;
    by = f2 / gx;
  }

  const int mBase = by * 128;
  const int nBase = bx * 128;

  const bf16_t* aTile = A + (size_t)mBase * K;
  const bf16_t* bTile = Bt + (size_t)nBase * K;

  f32x16 acc[2][2];
#pragma unroll
  for (int i = 0; i < 2; ++i)
#pragma unroll
    for (int j = 0; j < 2; ++j)
      acc[i][j] = (f32x16){0.f, 0.f, 0.f, 0.f, 0.f, 0.f, 0.f, 0.f,
                           0.f, 0.f, 0.f, 0.f, 0.f, 0.f, 0.f, 0.f};

  const int srow = tid >> 3;                              // 0..31 (row within 32-row pass)
  const int scb = (((tid & 7) ^ ((tid >> 3) & 7)) * 8);   // swizzled global chunk for this lane

  const int r7 = l31 & 7;                 // read-side swizzle key
  const int baseA = (wy * 64 + l31) * 64; // element offset of this lane's A row
  const int baseB = (wx * 64 + l31) * 64;

  for (int k0 = 0; k0 < K; k0 += 64) {
    // ---- stage A,B tiles (128 x 64 bf16 each) via async global->LDS, 16B/lane
#pragma unroll
    for (int p = 0; p < 4; ++p) {
      const int row = p * 32 + srow;
      const size_t go = (size_t)row * K + k0 + scb;
      const int lo = (p * 256 + wv * 64) * 8;  // wave-uniform segment base (elements)
      async_copy16(aTile + go, As + lo);
      async_copy16(bTile + go, Bs + lo);
    }
    __syncthreads();  // drains vmcnt: tiles resident

    // ---- compute: 4 k-substeps of 16, 4 MFMA (32x32x16) each per wave
#pragma unroll
    for (int ks = 0; ks < 4; ++ks) {
      const int phys = ((ks * 2 + lh) ^ r7) * 8;  // physical chunk offset (elements)
      bf16x8 af[2], bfr[2];
#pragma unroll
      for (int i = 0; i < 2; ++i) {
        af[i]  = *(const bf16x8*)(As + baseA + i * 32 * 64 + phys);
        bfr[i] = *(const bf16x8*)(Bs + baseB + i * 32 * 64 + phys);
      }
#pragma unroll
      for (int i = 0; i < 2; ++i)
#pragma unroll
        for (int j = 0; j < 2; ++j)
          acc[i][j] = __builtin_amdgcn_mfma_f32_32x32x16_bf16(af[i], bfr[j], acc[i][j], 0, 0, 0);
    }
    __syncthreads();  // all waves done reading before next stage
  }

  // ---- epilogue: bias + quantize (+ PWL GELU via register-table shuffle)
  float bj[2];
#pragma unroll
  for (int j = 0; j < 2; ++j)
    bj[j] = bias[nBase + wx * 64 + j * 32 + l31];

#pragma unroll
  for (int i = 0; i < 2; ++i) {
#pragma unroll
    for (int j = 0; j < 2; ++j) {
      const int cn = nBase + wx * 64 + j * 32 + l31;
#pragma unroll
      for (int reg = 0; reg < 16; ++reg) {
        const int rm = mBase + wy * 64 + i * 32 + (reg & 3) + 8 * (reg >> 2) + 4 * lh;
        float c = acc[i][j][reg] + bj[j];
        float v;
        if (GELU) {
          float xq = rintf(c * QS) * QINV;           // float2fix (Positional_0)
          float t = (xq + 4.0f) * 4.0f;              // exact: /0.25
          int ii = (int)t;
          ii = ii < 0 ? 0 : (ii > 31 ? 31 : ii);
          float f = t - (float)ii;
          float y0 = __shfl(ytA, ii);
          float sl = __shfl(ytS, ii);
          v = fmaf(f, sl, y0);
          v = (xq > 4.0f) ? xq : v;
          v = (xq < -4.0f) ? 0.0f : v;
          v = rintf(v * QS) * QINV;                  // quantize out (+Positional_1 idempotent)
        } else {
          v = rintf(c * QS) * QINV;                  // Positional_2
        }
        C[(size_t)rm * N + cn] = (OutT)v;
      }
    }
  }
}

// Fused prep: one launch replaces cvt_bf16 + 2 transposes (saves 2 launch gaps).
// blocks [0,16384): x f32 -> xb bf16 (float4/thread)
// blocks [16384,20480): w1 [1024][4096] -> w1t [4096][1024] bf16
// blocks [20480,24576): w2 [4096][1024] -> w2t [1024][4096] bf16
__global__ __launch_bounds__(256)
void prep_kernel(const float* __restrict__ x, bf16_t* __restrict__ xb,
                 const float* __restrict__ w1, bf16_t* __restrict__ w1t,
                 const float* __restrict__ w2, bf16_t* __restrict__ w2t) {
  __shared__ float t[32][33];
  const int id = blockIdx.x;
  const int tid = threadIdx.x;
  if (id < 16384) {
    const int idx = id * 256 + tid;
    const float4 v = ((const float4*)x)[idx];
    bf16x4 o;
    o[0] = (bf16_t)v.x; o[1] = (bf16_t)v.y; o[2] = (bf16_t)v.z; o[3] = (bf16_t)v.w;
    ((bf16x4*)xb)[idx] = o;
  } else {
    const float* in; bf16_t* out; int R, C, bx, by;
    if (id < 20480) {  // w1: R=1024 rows, C=4096 cols; grid (128, 32)
      const int id2 = id - 16384;
      in = w1; out = w1t; R = 1024; C = 4096;
      bx = id2 & 127; by = id2 >> 7;
    } else {           // w2: R=4096 rows, C=1024 cols; grid (32, 128)
      const int id3 = id - 20480;
      in = w2; out = w2t; R = 4096; C = 1024;
      bx = id3 & 31; by = id3 >> 5;
    }
    const int c0 = bx * 32;
    const int r0 = by * 32;
    const int tx = tid & 31;
    const int ty = tid >> 5;  // 0..7
#pragma unroll
    for (int dy = 0; dy < 32; dy += 8)
      t[ty + dy][tx] = in[(size_t)(r0 + ty + dy) * C + c0 + tx];
    __syncthreads();
#pragma unroll
    for (int dy = 0; dy < 32; dy += 8)
      out[(size_t)(c0 + ty + dy) * R + r0 + tx] = (bf16_t)t[tx][ty + dy];
  }
}

extern "C" void kernel_launch(void* const* d_in, const int* in_sizes, int n_in,
                              void* d_out, int out_size, void* d_ws, size_t ws_size,
                              hipStream_t stream) {
  const float* x  = (const float*)d_in[0];   // [32,512,1024] = [16384][1024]
  const float* w1 = (const float*)d_in[1];   // [1024][4096]
  const float* b1 = (const float*)d_in[2];   // [4096]
  const float* w2 = (const float*)d_in[3];   // [4096][1024]
  const float* b2 = (const float*)d_in[4];   // [1024]
  float* out = (float*)d_out;                // [16384][1024]

  const int M = 16384, D = 1024, F = 4096;

  char* ws = (char*)d_ws;
  size_t off = 0;
  bf16_t* xb  = (bf16_t*)(ws + off); off += (size_t)M * D * 2;  // 33.5 MB
  bf16_t* w1t = (bf16_t*)(ws + off); off += (size_t)D * F * 2;  //  8.4 MB
  bf16_t* w2t = (bf16_t*)(ws + off); off += (size_t)F * D * 2;  //  8.4 MB
  bf16_t* h   = (bf16_t*)(ws + off);                            // 134.2 MB

  // fused cvt + transposes (single launch)
  prep_kernel<<<16384 + 4096 + 4096, 256, 0, stream>>>(x, xb, w1, w1t, w2, w2t);

  // GEMM1 + quantize + PWL-GELU + quantize -> h (bf16); NO swizzle (r6: hurts)
  gemm_tile<true, bf16_t, false><<<dim3(F / 128, M / 128), 256, 0, stream>>>(xb, w1t, b1, h, M, F, D);
  // GEMM2 + quantize -> out (f32); XCD-chunked swizzle (B-panel 1MB fits L2)
  gemm_tile<false, float, true><<<dim3(D / 128, M / 128), 256, 0, stream>>>(h, w2t, b2, out, M, D, F);
}

// Round 8
// 424.264 us; speedup vs baseline: 1.0556x; 1.0556x over previous
//
#include <hip/hip_runtime.h>
#include <hip/hip_bf16.h>

typedef __bf16 bf16_t;
typedef __bf16 bf16x8 __attribute__((ext_vector_type(8)));
typedef __bf16 bf16x4 __attribute__((ext_vector_type(4)));
typedef float f32x4 __attribute__((ext_vector_type(4)));

#define QS   256.0f
#define QINV 0.00390625f

__device__ __forceinline__ void async_copy16(const bf16_t* g, bf16_t* l) {
  __builtin_amdgcn_global_load_lds(
      (__attribute__((address_space(1))) void*)g,
      (__attribute__((address_space(3))) void*)l,
      16, 0, 0);
}

// Stage one 16KB unit (128 rows x 64 cols bf16) of a 256x64 tile into LDS.
// SHIFT=6 (A units: 64-row segments), SHIFT=5 (B units: 32-row segments).
// halfOff selects which interleaved half (A: 0/64, B: 0/32).
// Global chunk pre-permuted so linear LDS dest ends up XOR-swizzled:
// phys chunk c of row r holds logical chunk c ^ (r & 7).
template <int SHIFT>
__device__ __forceinline__ void stage_unit(const bf16_t* __restrict__ gk, bf16_t* lbuf,
                                           int K, int halfOff, int tid) {
  const int scb = (((tid & 7) ^ ((tid >> 3) & 7)) << 3);  // swizzled global chunk (elems)
  const int MASK = (1 << SHIFT) - 1;
#pragma unroll
  for (int q = 0; q < 2; ++q) {
    const int u  = q * 64 + (tid >> 3);          // per-lane unit-row
    const int u0 = q * 64 + ((tid >> 6) << 3);   // wave-uniform base unit-row
    const int row  = halfOff + (u  & MASK) + ((u  >> SHIFT) << (SHIFT + 1));
    const int row0 = halfOff + (u0 & MASK) + ((u0 >> SHIFT) << (SHIFT + 1));
    async_copy16(gk + (size_t)row * K + scb, lbuf + row0 * 64);
  }
}

// read-side swizzle: physical chunk = logical ^ (row & 7)
__device__ __forceinline__ bf16x8 ldfrag(const bf16_t* buf, int row, int ks, int lq) {
  const int phys = ((ks << 2) | lq) ^ (row & 7);
  return *(const bf16x8*)(buf + row * 64 + (phys << 3));
}

// One K-tile (BK=64): 4 phases, each {ds_read frags | [stage T+2] | [counted
// vmcnt] | barrier | lgkmcnt(0)+sched_barrier | setprio+16 MFMA | barrier}.
// DEEP-SLACK wait schedule (r7 fix): tile T's units are staged during tile
// T-2 (P2: U0U1, P3: U2U3 into T's parity buffer -- regions dead by then);
// exactly two waits per tile, each retiring a group issued FIVE phases
// earlier (~3500cy slack >> 900cy HBM latency):
//   P0: vmcnt(8)  -> retires [U2U3(T)]   (read at P1/P2 of this tile)
//   P3: vmcnt(12) -> retires [U0U1(T+1)] (read at P0 of next tile)
// FIFO trace (16 loads max outstanding) verified incl. tail clamps.
__device__ __forceinline__ void ktile(
    const bf16_t* __restrict__ Ab, const bf16_t* __restrict__ Bb,
    bf16_t* __restrict__ Aw, bf16_t* __restrict__ Bw,     // stage dest (same parity, tile T+2)
    const bf16_t* __restrict__ aN2, const bf16_t* __restrict__ bN2,
    const bool stage2, const int wsel0, const int wsel3,
    const int tid, const int rA0, const int rB0, const int lq,
    const int K, f32x4 (&acc)[8][4]) {
  bf16x8 fa[2][4];      // A frags [ks][i], current i-half
  bf16x8 fb[2][2][2];   // B frags [jh][ks][j], both j-halves live

  // -------- P0: reads U0 (fa half0) + U1 (fb0); wait guards U2U3(T); MFMA Q00
#pragma unroll
  for (int ks = 0; ks < 2; ++ks) {
#pragma unroll
    for (int i = 0; i < 4; ++i) fa[ks][i] = ldfrag(Ab, rA0 + i * 16, ks, lq);
#pragma unroll
    for (int j = 0; j < 2; ++j) fb[0][ks][j] = ldfrag(Bb, rB0 + j * 16, ks, lq);
  }
  if (wsel0 == 0) { asm volatile("s_waitcnt vmcnt(8)" ::: "memory"); }
  else            { asm volatile("s_waitcnt vmcnt(0)" ::: "memory"); }
  __builtin_amdgcn_s_barrier();
  asm volatile("s_waitcnt lgkmcnt(0)" ::: "memory");
  __builtin_amdgcn_sched_barrier(0);
  __builtin_amdgcn_s_setprio(1);
#pragma unroll
  for (int ks = 0; ks < 2; ++ks)
#pragma unroll
    for (int i = 0; i < 4; ++i)
#pragma unroll
      for (int j = 0; j < 2; ++j)
        acc[i][j] = __builtin_amdgcn_mfma_f32_16x16x32_bf16(fa[ks][i], fb[0][ks][j], acc[i][j], 0, 0, 0);
  __builtin_amdgcn_s_setprio(0);
  __builtin_amdgcn_s_barrier();

  // -------- P1: reads U2 (fb1); MFMA Q01
#pragma unroll
  for (int ks = 0; ks < 2; ++ks)
#pragma unroll
    for (int j = 0; j < 2; ++j) fb[1][ks][j] = ldfrag(Bb, rB0 + 32 + j * 16, ks, lq);
  __builtin_amdgcn_s_barrier();
  asm volatile("s_waitcnt lgkmcnt(0)" ::: "memory");
  __builtin_amdgcn_sched_barrier(0);
  __builtin_amdgcn_s_setprio(1);
#pragma unroll
  for (int ks = 0; ks < 2; ++ks)
#pragma unroll
    for (int i = 0; i < 4; ++i)
#pragma unroll
      for (int j = 0; j < 2; ++j)
        acc[i][2 + j] = __builtin_amdgcn_mfma_f32_16x16x32_bf16(fa[ks][i], fb[1][ks][j], acc[i][2 + j], 0, 0, 0);
  __builtin_amdgcn_s_setprio(0);
  __builtin_amdgcn_s_barrier();

  // -------- P2: reads U3 (fa half1); stage U0U1(T+2) into own buffer; MFMA Q11
#pragma unroll
  for (int ks = 0; ks < 2; ++ks)
#pragma unroll
    for (int i = 0; i < 4; ++i) fa[ks][i] = ldfrag(Ab, rA0 + 64 + i * 16, ks, lq);
  if (stage2) {
    stage_unit<6>(aN2, Aw, K, 0, tid);   // U0(T+2): A rows dead since P0
    stage_unit<5>(bN2, Bw, K, 0, tid);   // U1(T+2): B rows dead since P0
  }
  __builtin_amdgcn_s_barrier();
  asm volatile("s_waitcnt lgkmcnt(0)" ::: "memory");
  __builtin_amdgcn_sched_barrier(0);
  __builtin_amdgcn_s_setprio(1);
#pragma unroll
  for (int ks = 0; ks < 2; ++ks)
#pragma unroll
    for (int i = 0; i < 4; ++i)
#pragma unroll
      for (int j = 0; j < 2; ++j)
        acc[4 + i][2 + j] = __builtin_amdgcn_mfma_f32_16x16x32_bf16(fa[ks][i], fb[1][ks][j], acc[4 + i][2 + j], 0, 0, 0);
  __builtin_amdgcn_s_setprio(0);
  __builtin_amdgcn_s_barrier();

  // -------- P3: stage U2U3(T+2); wait guards U0U1(T+1); MFMA Q10
  if (stage2) {
    stage_unit<5>(bN2, Bw, K, 32, tid);  // U2(T+2): B rows dead since P1
    stage_unit<6>(aN2, Aw, K, 64, tid);  // U3(T+2): A rows dead since P2
  }
  if (wsel3 == 0)      { asm volatile("s_waitcnt vmcnt(12)" ::: "memory"); }
  else if (wsel3 == 1) { asm volatile("s_waitcnt vmcnt(4)"  ::: "memory"); }
  __builtin_amdgcn_s_barrier();
  __builtin_amdgcn_sched_barrier(0);
  __builtin_amdgcn_s_setprio(1);
#pragma unroll
  for (int ks = 0; ks < 2; ++ks)
#pragma unroll
    for (int i = 0; i < 4; ++i)
#pragma unroll
      for (int j = 0; j < 2; ++j)
        acc[4 + i][j] = __builtin_amdgcn_mfma_f32_16x16x32_bf16(fa[ks][i], fb[0][ks][j], acc[4 + i][j], 0, 0, 0);
  __builtin_amdgcn_s_setprio(0);
  __builtin_amdgcn_s_barrier();
}

// C = quantize-epilogue(A @ Bt^T + bias)
// 256x256 tile, BK=64, 8 waves (2Mx4N), per-wave 128x64 via acc[8][4].
// Deep-slack pipeline: 2 tiles staged ahead, 2 counted vmcnt per K-tile,
// each with >=5 phases between stage-issue and wait. nT even, >=4.
template <bool GELU, typename OutT, bool XSWZ>
__global__ __launch_bounds__(512, 2)
void gemm_tile(const bf16_t* __restrict__ A, const bf16_t* __restrict__ Bt,
               const float* __restrict__ bias, OutT* __restrict__ C,
               int M, int N, int K) {
  __shared__ __attribute__((aligned(16))) bf16_t As0[256 * 64];
  __shared__ __attribute__((aligned(16))) bf16_t Bs0[256 * 64];
  __shared__ __attribute__((aligned(16))) bf16_t As1[256 * 64];
  __shared__ __attribute__((aligned(16))) bf16_t Bs1[256 * 64];

  const int tid = threadIdx.x;
  const int lane = tid & 63;
  const int wid = tid >> 6;   // 0..7
  const int wr = wid >> 2;    // wave row (0/1) -> 128 rows
  const int wc = wid & 3;     // wave col (0..3) -> 64 cols
  const int l15 = lane & 15;
  const int lq = lane >> 4;   // 0..3

  // register-resident PWL table: lane l holds y(x_l) and slope to x_{l+1}
  float ytA = 0.f, ytS = 0.f;
  if (GELU) {
    float xv = -4.0f + 0.25f * (float)lane;
    float y0 = 0.5f * xv * (1.0f + erff(xv * 0.70710678f));
    float xv1 = xv + 0.25f;
    float y1 = 0.5f * xv1 * (1.0f + erff(xv1 * 0.70710678f));
    ytA = y0;
    ytS = y1 - y0;
  }

  int bx = blockIdx.x, by = blockIdx.y;
  if (XSWZ) {
    // bijective XCD-chunked remap (helps when per-XCD reuse panel fits L2:
    // GEMM2 B-panel 1MB). GEMM1 uses XSWZ=false (r6: 8.4MB panel thrashes).
    const int gx = gridDim.x;
    const int nwg = gx * gridDim.y;       // divisible by 8 here
    const int f = by * gx + bx;
    const int chunk = nwg >> 3;
    const int f2 = (f & 7) * chunk + (f >> 3);
    bx = f2 % gx;
    by = f2 / gx;
  }

  const int mBase = by * 256;
  const int nBase = bx * 256;
  const bf16_t* aTile = A + (size_t)mBase * K;
  const bf16_t* bTile = Bt + (size_t)nBase * K;

  f32x4 acc[8][4];
#pragma unroll
  for (int i = 0; i < 8; ++i)
#pragma unroll
    for (int j = 0; j < 4; ++j)
      acc[i][j] = (f32x4){0.f, 0.f, 0.f, 0.f};

  const int nT = K >> 6;  // 16 (GEMM1) / 64 (GEMM2): even, >=4
  const int rA0 = wr * 128 + l15;
  const int rB0 = wc * 64 + l15;

  // ---- prologue: stage tiles 0 and 1 fully (4 groups of 4 loads, FIFO order)
  stage_unit<6>(aTile, As0, K, 0, tid);         // [U0U1(0)]
  stage_unit<5>(bTile, Bs0, K, 0, tid);
  stage_unit<5>(bTile, Bs0, K, 32, tid);        // [U2U3(0)]
  stage_unit<6>(aTile, As0, K, 64, tid);
  stage_unit<6>(aTile + 64, As1, K, 0, tid);    // [U0U1(1)]
  stage_unit<5>(bTile + 64, Bs1, K, 0, tid);
  stage_unit<5>(bTile + 64, Bs1, K, 32, tid);   // [U2U3(1)]
  stage_unit<6>(aTile + 64, As1, K, 64, tid);
  asm volatile("s_waitcnt vmcnt(12)" ::: "memory");  // [U0U1(0)] resident
  __builtin_amdgcn_s_barrier();

  for (int tt = 0; tt < nT; tt += 2) {
    // tile tt (even, buffers 0); never the last tile (nT even)
    ktile(As0, Bs0, As0, Bs0,
          aTile + (size_t)(tt + 2) * 64, bTile + (size_t)(tt + 2) * 64,
          tt + 2 < nT, 0, (tt + 2 < nT) ? 0 : 1,
          tid, rA0, rB0, lq, K, acc);
    // tile tt+1 (odd, buffers 1)
    ktile(As1, Bs1, As1, Bs1,
          aTile + (size_t)(tt + 3) * 64, bTile + (size_t)(tt + 3) * 64,
          tt + 3 < nT, (tt + 1 == nT - 1) ? 1 : 0,
          (tt + 3 < nT) ? 0 : ((tt + 2 < nT) ? 1 : 2),
          tid, rA0, rB0, lq, K, acc);
  }

  // ---- epilogue: bias + quantize (+ PWL GELU via register-table shuffle)
  float bj[4];
#pragma unroll
  for (int j = 0; j < 4; ++j)
    bj[j] = bias[nBase + wc * 64 + j * 16 + l15];

#pragma unroll
  for (int i = 0; i < 8; ++i) {
    const int rb = mBase + wr * 128 + i * 16 + lq * 4;
#pragma unroll
    for (int j = 0; j < 4; ++j) {
      const int cn = nBase + wc * 64 + j * 16 + l15;
#pragma unroll
      for (int r = 0; r < 4; ++r) {
        float c = acc[i][j][r] + bj[j];
        float v;
        if (GELU) {
          float xq = rintf(c * QS) * QINV;           // float2fix (Positional_0)
          float t = (xq + 4.0f) * 4.0f;              // exact: /0.25
          int ii = (int)t;
          ii = ii < 0 ? 0 : (ii > 31 ? 31 : ii);
          float f = t - (float)ii;
          float y0 = __shfl(ytA, ii);
          float sl = __shfl(ytS, ii);
          v = fmaf(f, sl, y0);
          v = (xq > 4.0f) ? xq : v;
          v = (xq < -4.0f) ? 0.0f : v;
          v = rintf(v * QS) * QINV;                  // quantize out (+Positional_1 idempotent)
        } else {
          v = rintf(c * QS) * QINV;                  // Positional_2
        }
        C[(size_t)(rb + r) * N + cn] = (OutT)v;
      }
    }
  }
}

// Fused prep: one launch replaces cvt_bf16 + 2 transposes (saves 2 launch gaps).
__global__ __launch_bounds__(256)
void prep_kernel(const float* __restrict__ x, bf16_t* __restrict__ xb,
                 const float* __restrict__ w1, bf16_t* __restrict__ w1t,
                 const float* __restrict__ w2, bf16_t* __restrict__ w2t) {
  __shared__ float t[32][33];
  const int id = blockIdx.x;
  const int tid = threadIdx.x;
  if (id < 16384) {
    const int idx = id * 256 + tid;
    const float4 v = ((const float4*)x)[idx];
    bf16x4 o;
    o[0] = (bf16_t)v.x; o[1] = (bf16_t)v.y; o[2] = (bf16_t)v.z; o[3] = (bf16_t)v.w;
    ((bf16x4*)xb)[idx] = o;
  } else {
    const float* in; bf16_t* out; int R, C, bx, by;
    if (id < 20480) {  // w1: R=1024 rows, C=4096 cols; grid (128, 32)
      const int id2 = id - 16384;
      in = w1; out = w1t; R = 1024; C = 4096;
      bx = id2 & 127; by = id2 >> 7;
    } else {           // w2: R=4096 rows, C=1024 cols; grid (32, 128)
      const int id3 = id - 20480;
      in = w2; out = w2t; R = 4096; C = 1024;
      bx = id3 & 31; by = id3 >> 5;
    }
    const int c0 = bx * 32;
    const int r0 = by * 32;
    const int tx = tid & 31;
    const int ty = tid >> 5;  // 0..7
#pragma unroll
    for (int dy = 0; dy < 32; dy += 8)
      t[ty + dy][tx] = in[(size_t)(r0 + ty + dy) * C + c0 + tx];
    __syncthreads();
#pragma unroll
    for (int dy = 0; dy < 32; dy += 8)
      out[(size_t)(c0 + ty + dy) * R + r0 + tx] = (bf16_t)t[tx][ty + dy];
  }
}

extern "C" void kernel_launch(void* const* d_in, const int* in_sizes, int n_in,
                              void* d_out, int out_size, void* d_ws, size_t ws_size,
                              hipStream_t stream) {
  const float* x  = (const float*)d_in[0];   // [32,512,1024] = [16384][1024]
  const float* w1 = (const float*)d_in[1];   // [1024][4096]
  const float* b1 = (const float*)d_in[2];   // [4096]
  const float* w2 = (const float*)d_in[3];   // [4096][1024]
  const float* b2 = (const float*)d_in[4];   // [1024]
  float* out = (float*)d_out;                // [16384][1024]

  const int M = 16384, D = 1024, F = 4096;

  char* ws = (char*)d_ws;
  size_t off = 0;
  bf16_t* xb  = (bf16_t*)(ws + off); off += (size_t)M * D * 2;  // 33.5 MB
  bf16_t* w1t = (bf16_t*)(ws + off); off += (size_t)D * F * 2;  //  8.4 MB
  bf16_t* w2t = (bf16_t*)(ws + off); off += (size_t)F * D * 2;  //  8.4 MB
  bf16_t* h   = (bf16_t*)(ws + off);                            // 134.2 MB

  // fused cvt + transposes (single launch)
  prep_kernel<<<16384 + 4096 + 4096, 256, 0, stream>>>(x, xb, w1, w1t, w2, w2t);

  // GEMM1 + quantize + PWL-GELU + quantize -> h (bf16); no swizzle (r6)
  gemm_tile<true, bf16_t, false><<<dim3(F / 256, M / 256), 512, 0, stream>>>(xb, w1t, b1, h, M, F, D);
  // GEMM2 + quantize -> out (f32); XCD-chunked swizzle
  gemm_tile<false, float, true><<<dim3(D / 256, M / 256), 512, 0, stream>>>(h, w2t, b2, out, M, D, F);
}